// Round 1
// baseline (1478.635 us; speedup 1.0000x reference)
//
#include <hip/hip_runtime.h>
#include <stdint.h>

#define FEAT_IN 128
#define F1 32
#define F2 64
#define FJ 96
#define FH 128

// ---- degree (in-degree; +1 self-loop added in dinv) ----
__global__ void deg_kernel(const int* __restrict__ dst, float* __restrict__ degf, int nE) {
    int e = blockIdx.x * blockDim.x + threadIdx.x;
    if (e < nE) atomicAdd(&degf[dst[e]], 1.0f);
}

__global__ void dinv_kernel(const float* __restrict__ degf, float* __restrict__ dinv, int nN) {
    int i = blockIdx.x * blockDim.x + threadIdx.x;
    if (i < nN) dinv[i] = rsqrtf(degf[i] + 1.0f);
}

// ---- g1 = (x @ W1) * dinv ; A1 initialized to g1 (self-loop term) ----
__global__ void gemm1_kernel(const float* __restrict__ x, const float* __restrict__ W1,
                             const float* __restrict__ dinv,
                             float* __restrict__ g1, float* __restrict__ A1, int nN) {
    __shared__ float Ws[FEAT_IN * F1];
    for (int t = threadIdx.x; t < FEAT_IN * F1; t += blockDim.x) Ws[t] = W1[t];
    __syncthreads();
    int row = blockIdx.x * 8 + (threadIdx.x >> 5);
    if (row >= nN) return;
    int j = threadIdx.x & 31;
    const float* xr = x + (size_t)row * FEAT_IN;
    float acc = 0.f;
#pragma unroll 8
    for (int k = 0; k < FEAT_IN; ++k) acc = fmaf(xr[k], Ws[k * F1 + j], acc);
    float g = acc * dinv[row];
    g1[row * F1 + j] = g;
    A1[row * F1 + j] = g;
}

// ---- edge scatter conv1: 32 lanes per edge ----
__global__ void scatter1_kernel(const int* __restrict__ src, const int* __restrict__ dst,
                                const float* __restrict__ g1, float* __restrict__ A1, int nE) {
    unsigned gid = blockIdx.x * blockDim.x + threadIdx.x;
    int e = gid >> 5;
    if (e >= nE) return;
    int j = gid & 31;
    int s = src[e], d = dst[e];
    atomicAdd(&A1[d * F1 + j], g1[s * F1 + j]);
}

// ---- x1 = relu(dinv * A1 + b1), in place ----
__global__ void fin1_kernel(const float* __restrict__ dinv, const float* __restrict__ b1,
                            float* __restrict__ A1, int nN) {
    int gid = blockIdx.x * blockDim.x + threadIdx.x;
    if (gid >= nN * F1) return;
    int i = gid >> 5, j = gid & 31;
    float v = dinv[i] * A1[gid] + b1[j];
    A1[gid] = v > 0.f ? v : 0.f;
}

// ---- g2 = (x1 @ W2) * dinv ; A2 = g2 ----
__global__ void gemm2_kernel(const float* __restrict__ x1, const float* __restrict__ W2,
                             const float* __restrict__ dinv,
                             float* __restrict__ g2, float* __restrict__ A2, int nN) {
    __shared__ float Ws[F1 * F2];
    for (int t = threadIdx.x; t < F1 * F2; t += blockDim.x) Ws[t] = W2[t];
    __syncthreads();
    int row = blockIdx.x * 4 + (threadIdx.x >> 6);
    if (row >= nN) return;
    int j = threadIdx.x & 63;
    const float* xr = x1 + (size_t)row * F1;
    float acc = 0.f;
#pragma unroll
    for (int k = 0; k < F1; ++k) acc = fmaf(xr[k], Ws[k * F2 + j], acc);
    float g = acc * dinv[row];
    g2[row * F2 + j] = g;
    A2[row * F2 + j] = g;
}

// ---- edge scatter conv2: 64 lanes per edge ----
__global__ void scatter2_kernel(const int* __restrict__ src, const int* __restrict__ dst,
                                const float* __restrict__ g2, float* __restrict__ A2, int nE) {
    unsigned gid = blockIdx.x * blockDim.x + threadIdx.x;
    int e = gid >> 6;
    if (e >= nE) return;
    int j = gid & 63;
    int s = src[e], d = dst[e];
    atomicAdd(&A2[d * F2 + j], g2[s * F2 + j]);
}

// ---- x2 = relu(dinv * A2 + b2), in place ----
__global__ void fin2_kernel(const float* __restrict__ dinv, const float* __restrict__ b2,
                            float* __restrict__ A2, int nN) {
    int gid = blockIdx.x * blockDim.x + threadIdx.x;
    if (gid >= nN * F2) return;
    int i = gid >> 6, j = gid & 63;
    float v = dinv[i] * A2[gid] + b2[j];
    A2[gid] = v > 0.f ? v : 0.f;
}

// ---- pooling sums: atomics into psum[512*96] ----
__global__ void pool_kernel(const float* __restrict__ x1, const float* __restrict__ x2,
                            const int* __restrict__ batch, float* __restrict__ psum, int nN) {
    unsigned gid = blockIdx.x * blockDim.x + threadIdx.x;
    unsigned total = (unsigned)nN * FJ;
    if (gid >= total) return;
    int i = gid / FJ, f = gid % FJ;
    int b = batch[i];
    float v = (f < F1) ? x1[i * F1 + f] : x2[i * F2 + (f - F1)];
    atomicAdd(&psum[b * FJ + f], v);
}

__global__ void cnt_kernel(const int* __restrict__ batch, float* __restrict__ cnt, int nN) {
    int i = blockIdx.x * blockDim.x + threadIdx.x;
    if (i < nN) atomicAdd(&cnt[batch[i]], 1.0f);
}

// ---- final MLP: one block (128 thr) per graph ----
__global__ void mlp_kernel(const float* __restrict__ psum, const float* __restrict__ cnt,
                           const float* __restrict__ fW1, const float* __restrict__ fb1,
                           const float* __restrict__ fW2, const float* __restrict__ fb2,
                           float* __restrict__ out) {
    __shared__ float p[FJ];
    __shared__ float red[FH];
    int g = blockIdx.x, tid = threadIdx.x;
    float c = fmaxf(cnt[g], 1.0f);
    if (tid < FJ) p[tid] = psum[g * FJ + tid] / c;
    __syncthreads();
    float acc = fb1[tid];
    for (int k = 0; k < FJ; ++k) acc = fmaf(p[k], fW1[k * FH + tid], acc);
    float h = fmaxf(acc, 0.f);
    red[tid] = h * fW2[tid];
    __syncthreads();
    for (int s = FH / 2; s > 0; s >>= 1) {
        if (tid < s) red[tid] += red[tid + s];
        __syncthreads();
    }
    if (tid == 0) out[g] = red[0] + fb2[0];
}

extern "C" void kernel_launch(void* const* d_in, const int* in_sizes, int n_in,
                              void* d_out, int out_size, void* d_ws, size_t ws_size,
                              hipStream_t stream) {
    const float* x   = (const float*)d_in[0];
    const int*   ei  = (const int*)d_in[1];
    const int*   bat = (const int*)d_in[2];
    const float* W1  = (const float*)d_in[3];
    const float* b1  = (const float*)d_in[4];
    const float* W2  = (const float*)d_in[5];
    const float* b2  = (const float*)d_in[6];
    const float* fW1 = (const float*)d_in[7];
    const float* fb1 = (const float*)d_in[8];
    const float* fW2 = (const float*)d_in[9];
    const float* fb2 = (const float*)d_in[10];
    float* out = (float*)d_out;

    int nN = in_sizes[0] / FEAT_IN;
    int nE = in_sizes[1] / 2;
    int nG = out_size;
    const int* src = ei;
    const int* dst = ei + nE;

    float* w = (float*)d_ws;
    float* degf = w;  w += nN;
    float* dinv = w;  w += nN;
    float* g1   = w;  w += (size_t)nN * F1;
    float* A1   = w;  w += (size_t)nN * F1;   // becomes x1 after fin1
    float* g2   = w;  w += (size_t)nN * F2;
    float* A2   = w;  w += (size_t)nN * F2;   // becomes x2 after fin2
    float* psum = w;  w += (size_t)nG * FJ;
    float* cnt  = w;  w += nG;

    hipMemsetAsync(degf, 0, (size_t)nN * sizeof(float), stream);
    hipMemsetAsync(psum, 0, ((size_t)nG * FJ + nG) * sizeof(float), stream);

    deg_kernel<<<(nE + 255) / 256, 256, 0, stream>>>(dst, degf, nE);
    dinv_kernel<<<(nN + 255) / 256, 256, 0, stream>>>(degf, dinv, nN);
    gemm1_kernel<<<(nN + 7) / 8, 256, 0, stream>>>(x, W1, dinv, g1, A1, nN);
    {
        unsigned blocks = (unsigned)(((long long)nE * F1 + 255) / 256);
        scatter1_kernel<<<blocks, 256, 0, stream>>>(src, dst, g1, A1, nE);
    }
    fin1_kernel<<<(nN * F1 + 255) / 256, 256, 0, stream>>>(dinv, b1, A1, nN);
    gemm2_kernel<<<(nN + 3) / 4, 256, 0, stream>>>(A1, W2, dinv, g2, A2, nN);
    {
        unsigned blocks = (unsigned)(((long long)nE * F2 + 255) / 256);
        scatter2_kernel<<<blocks, 256, 0, stream>>>(src, dst, g2, A2, nE);
    }
    fin2_kernel<<<(nN * F2 + 255) / 256, 256, 0, stream>>>(dinv, b2, A2, nN);
    {
        unsigned blocks = (unsigned)(((long long)nN * FJ + 255) / 256);
        pool_kernel<<<blocks, 256, 0, stream>>>(A1, A2, bat, psum, nN);
    }
    cnt_kernel<<<(nN + 255) / 256, 256, 0, stream>>>(bat, cnt, nN);
    mlp_kernel<<<nG, FH, 0, stream>>>(psum, cnt, fW1, fb1, fW2, fb2, out);
}

// Round 2
// 1162.574 us; speedup vs baseline: 1.2719x; 1.2719x over previous
//
#include <hip/hip_runtime.h>
#include <stdint.h>

#define FEAT_IN 128
#define F1 32
#define F2 64
#define FJ 96
#define FH 128

// ---------- degree (in-degree, int) ----------
__global__ void deg_count(const int* __restrict__ dst, int* __restrict__ degi, int nE) {
    int e = blockIdx.x * blockDim.x + threadIdx.x;
    if (e < nE) atomicAdd(&degi[dst[e]], 1);
}

__global__ void dinv_kernel(const int* __restrict__ degi, float* __restrict__ dinv, int nN) {
    int i = blockIdx.x * blockDim.x + threadIdx.x;
    if (i < nN) dinv[i] = rsqrtf((float)degi[i] + 1.0f);
}

// ---------- 3-phase exclusive scan over degrees -> rowptr, cursor ----------
__global__ void scanA(const int* __restrict__ degi, int* __restrict__ bsum, int nN) {
    __shared__ int s[256];
    int b = blockIdx.x, t = threadIdx.x;
    int base = b * 1024 + t * 4;
    int sum = 0;
#pragma unroll
    for (int k = 0; k < 4; ++k) { int i = base + k; if (i < nN) sum += degi[i]; }
    s[t] = sum; __syncthreads();
    for (int off = 128; off > 0; off >>= 1) { if (t < off) s[t] += s[t + off]; __syncthreads(); }
    if (t == 0) bsum[b] = s[0];
}

__global__ void scanB(const int* __restrict__ bsum, int* __restrict__ boff, int nB,
                      int* __restrict__ rowptr, int nN) {
    if (threadIdx.x == 0) {
        int run = 0;
        for (int i = 0; i < nB; ++i) { boff[i] = run; run += bsum[i]; }
        rowptr[nN] = run;
    }
}

__global__ void scanC(const int* __restrict__ degi, const int* __restrict__ boff,
                      int* __restrict__ rowptr, int* __restrict__ cursor, int nN) {
    __shared__ int s[256];
    int b = blockIdx.x, t = threadIdx.x;
    int base = b * 1024 + t * 4;
    int d[4]; int sum = 0;
#pragma unroll
    for (int k = 0; k < 4; ++k) { int i = base + k; d[k] = (i < nN) ? degi[i] : 0; sum += d[k]; }
    s[t] = sum; __syncthreads();
    for (int off = 1; off < 256; off <<= 1) {
        int u = (t >= off) ? s[t - off] : 0; __syncthreads();
        s[t] += u; __syncthreads();
    }
    int excl = s[t] - sum + boff[b];
#pragma unroll
    for (int k = 0; k < 4; ++k) {
        int i = base + k;
        if (i < nN) { rowptr[i] = excl; cursor[i] = excl; excl += d[k]; }
    }
}

__global__ void csr_fill(const int* __restrict__ src, const int* __restrict__ dst,
                         int* __restrict__ cursor, int* __restrict__ csr, int nE) {
    int e = blockIdx.x * blockDim.x + threadIdx.x;
    if (e < nE) {
        int pos = atomicAdd(&cursor[dst[e]], 1);
        csr[pos] = src[e];
    }
}

// ---------- g1 = (x @ W1) * dinv, stride 32 ----------
__global__ void gemm1_kernel(const float* __restrict__ x, const float* __restrict__ W1,
                             const float* __restrict__ dinv, float* __restrict__ G, int nN) {
    __shared__ float Ws[FEAT_IN * F1];
    for (int t = threadIdx.x; t < FEAT_IN * F1; t += blockDim.x) Ws[t] = W1[t];
    __syncthreads();
    int row = blockIdx.x * 8 + (threadIdx.x >> 5);
    if (row >= nN) return;
    int j = threadIdx.x & 31;
    const float* xr = x + (size_t)row * FEAT_IN;
    float acc = 0.f;
#pragma unroll 8
    for (int k = 0; k < FEAT_IN; ++k) acc = fmaf(xr[k], Ws[k * F1 + j], acc);
    G[(size_t)row * F1 + j] = acc * dinv[row];
}

// ---------- x1 = relu(dinv * (self + sum_neighbors) + b1) ----------
__global__ void agg1_kernel(const int* __restrict__ rowptr, const int* __restrict__ csr,
                            const float* __restrict__ G, const float* __restrict__ dinv,
                            const float* __restrict__ b1, float* __restrict__ X1, int nN) {
    int node = blockIdx.x * (blockDim.x >> 5) + (threadIdx.x >> 5);
    if (node >= nN) return;
    int j = threadIdx.x & 31;
    int beg = rowptr[node], end = rowptr[node + 1];
    float acc = G[(size_t)node * F1 + j];   // self-loop
    for (int e = beg; e < end; ++e) {
        int s = csr[e];
        acc += G[(size_t)s * F1 + j];
    }
    float v = dinv[node] * acc + b1[j];
    X1[(size_t)node * F1 + j] = v > 0.f ? v : 0.f;
}

// ---------- g2 = (x1 @ W2) * dinv, stride 64 ----------
__global__ void gemm2_kernel(const float* __restrict__ x1, const float* __restrict__ W2,
                             const float* __restrict__ dinv, float* __restrict__ G, int nN) {
    __shared__ float Ws[F1 * F2];
    for (int t = threadIdx.x; t < F1 * F2; t += blockDim.x) Ws[t] = W2[t];
    __syncthreads();
    int row = blockIdx.x * 4 + (threadIdx.x >> 6);
    if (row >= nN) return;
    int j = threadIdx.x & 63;
    const float* xr = x1 + (size_t)row * F1;
    float acc = 0.f;
#pragma unroll
    for (int k = 0; k < F1; ++k) acc = fmaf(xr[k], Ws[k * F2 + j], acc);
    G[(size_t)row * F2 + j] = acc * dinv[row];
}

// ---------- x2 = relu(dinv * (self + sum_neighbors) + b2) ----------
__global__ void agg2_kernel(const int* __restrict__ rowptr, const int* __restrict__ csr,
                            const float* __restrict__ G, const float* __restrict__ dinv,
                            const float* __restrict__ b2, float* __restrict__ X2, int nN) {
    int node = blockIdx.x * (blockDim.x >> 6) + (threadIdx.x >> 6);
    if (node >= nN) return;
    int j = threadIdx.x & 63;
    int beg = rowptr[node], end = rowptr[node + 1];
    float acc = G[(size_t)node * F2 + j];   // self-loop
    for (int e = beg; e < end; ++e) {
        int s = csr[e];
        acc += G[(size_t)s * F2 + j];
    }
    float v = dinv[node] * acc + b2[j];
    X2[(size_t)node * F2 + j] = v > 0.f ? v : 0.f;
}

// ---------- pooling ----------
__global__ void pool_kernel(const float* __restrict__ x1, const float* __restrict__ x2,
                            const int* __restrict__ batch, float* __restrict__ psum, int nN) {
    unsigned gid = blockIdx.x * blockDim.x + threadIdx.x;
    unsigned total = (unsigned)nN * FJ;
    if (gid >= total) return;
    int i = gid / FJ, f = gid % FJ;
    int b = batch[i];
    float v = (f < F1) ? x1[i * F1 + f] : x2[i * F2 + (f - F1)];
    atomicAdd(&psum[b * FJ + f], v);
}

__global__ void cnt_kernel(const int* __restrict__ batch, float* __restrict__ cnt, int nN) {
    int i = blockIdx.x * blockDim.x + threadIdx.x;
    if (i < nN) atomicAdd(&cnt[batch[i]], 1.0f);
}

// ---------- final MLP: one block (128 thr) per graph ----------
__global__ void mlp_kernel(const float* __restrict__ psum, const float* __restrict__ cnt,
                           const float* __restrict__ fW1, const float* __restrict__ fb1,
                           const float* __restrict__ fW2, const float* __restrict__ fb2,
                           float* __restrict__ out) {
    __shared__ float p[FJ];
    __shared__ float red[FH];
    int g = blockIdx.x, tid = threadIdx.x;
    float c = fmaxf(cnt[g], 1.0f);
    if (tid < FJ) p[tid] = psum[g * FJ + tid] / c;
    __syncthreads();
    float acc = fb1[tid];
    for (int k = 0; k < FJ; ++k) acc = fmaf(p[k], fW1[k * FH + tid], acc);
    float h = fmaxf(acc, 0.f);
    red[tid] = h * fW2[tid];
    __syncthreads();
    for (int s = FH / 2; s > 0; s >>= 1) {
        if (tid < s) red[tid] += red[tid + s];
        __syncthreads();
    }
    if (tid == 0) out[g] = red[0] + fb2[0];
}

extern "C" void kernel_launch(void* const* d_in, const int* in_sizes, int n_in,
                              void* d_out, int out_size, void* d_ws, size_t ws_size,
                              hipStream_t stream) {
    const float* x   = (const float*)d_in[0];
    const int*   ei  = (const int*)d_in[1];
    const int*   bat = (const int*)d_in[2];
    const float* W1  = (const float*)d_in[3];
    const float* b1  = (const float*)d_in[4];
    const float* W2  = (const float*)d_in[5];
    const float* b2  = (const float*)d_in[6];
    const float* fW1 = (const float*)d_in[7];
    const float* fb1 = (const float*)d_in[8];
    const float* fW2 = (const float*)d_in[9];
    const float* fb2 = (const float*)d_in[10];
    float* out = (float*)d_out;

    int nN = in_sizes[0] / FEAT_IN;
    int nE = in_sizes[1] / 2;
    int nG = out_size;
    const int* src = ei;
    const int* dst = ei + nE;

    int nB = (nN + 1023) / 1024;

    char* w = (char*)d_ws;
    int* degi    = (int*)w;            w += (size_t)nN * 4;
    int* rowptr  = (int*)w;            w += (size_t)(nN + 1) * 4;
    int* cursor  = (int*)w;            w += (size_t)nN * 4;
    int* bsum    = (int*)w;            w += (size_t)nB * 4;
    int* boff    = (int*)w;            w += (size_t)nB * 4;
    int* csr     = (int*)w;            w += (size_t)nE * 4;
    float* dinv  = (float*)w;          w += (size_t)nN * 4;
    float* G     = (float*)w;          w += (size_t)nN * F2 * 4;  // g1 (stride 32) then g2 (stride 64)
    float* X1    = (float*)w;          w += (size_t)nN * F1 * 4;
    float* X2    = (float*)w;          w += (size_t)nN * F2 * 4;
    float* psum  = (float*)w;          w += (size_t)nG * FJ * 4;
    float* cnt   = (float*)w;          w += (size_t)nG * 4;

    hipMemsetAsync(degi, 0, (size_t)nN * sizeof(int), stream);
    hipMemsetAsync(psum, 0, ((size_t)nG * FJ + nG) * sizeof(float), stream);

    // CSR build
    deg_count<<<(nE + 255) / 256, 256, 0, stream>>>(dst, degi, nE);
    dinv_kernel<<<(nN + 255) / 256, 256, 0, stream>>>(degi, dinv, nN);
    scanA<<<nB, 256, 0, stream>>>(degi, bsum, nN);
    scanB<<<1, 64, 0, stream>>>(bsum, boff, nB, rowptr, nN);
    scanC<<<nB, 256, 0, stream>>>(degi, boff, rowptr, cursor, nN);
    csr_fill<<<(nE + 255) / 256, 256, 0, stream>>>(src, dst, cursor, csr, nE);

    // layer 1
    gemm1_kernel<<<(nN + 7) / 8, 256, 0, stream>>>(x, W1, dinv, G, nN);
    agg1_kernel<<<(nN + 7) / 8, 256, 0, stream>>>(rowptr, csr, G, dinv, b1, X1, nN);
    // layer 2
    gemm2_kernel<<<(nN + 3) / 4, 256, 0, stream>>>(X1, W2, dinv, G, nN);
    agg2_kernel<<<(nN + 3) / 4, 256, 0, stream>>>(rowptr, csr, G, dinv, b2, X2, nN);

    // pooling + MLP
    {
        unsigned blocks = (unsigned)(((long long)nN * FJ + 255) / 256);
        pool_kernel<<<blocks, 256, 0, stream>>>(X1, X2, bat, psum, nN);
    }
    cnt_kernel<<<(nN + 255) / 256, 256, 0, stream>>>(bat, cnt, nN);
    mlp_kernel<<<nG, FH, 0, stream>>>(psum, cnt, fW1, fb1, fW2, fb2, out);
}

// Round 3
// 871.611 us; speedup vs baseline: 1.6964x; 1.3338x over previous
//
#include <hip/hip_runtime.h>
#include <stdint.h>

#define FEAT_IN 128
#define F1 32
#define F2 64
#define FJ 96
#define FH 128

// ---------- degree (in-degree, int) ----------
__global__ void deg_count(const int* __restrict__ dst, int* __restrict__ degi, int nE) {
    int e = blockIdx.x * blockDim.x + threadIdx.x;
    if (e < nE) atomicAdd(&degi[dst[e]], 1);
}

__global__ void dinv_kernel(const int* __restrict__ degi, float* __restrict__ dinv, int nN) {
    int i = blockIdx.x * blockDim.x + threadIdx.x;
    if (i < nN) dinv[i] = rsqrtf((float)degi[i] + 1.0f);
}

// ---------- 3-phase exclusive scan over degrees -> rowptr, cursor ----------
__global__ void scanA(const int* __restrict__ degi, int* __restrict__ bsum, int nN) {
    __shared__ int s[256];
    int b = blockIdx.x, t = threadIdx.x;
    int base = b * 1024 + t * 4;
    int sum = 0;
#pragma unroll
    for (int k = 0; k < 4; ++k) { int i = base + k; if (i < nN) sum += degi[i]; }
    s[t] = sum; __syncthreads();
    for (int off = 128; off > 0; off >>= 1) { if (t < off) s[t] += s[t + off]; __syncthreads(); }
    if (t == 0) bsum[b] = s[0];
}

__global__ void scanB(const int* __restrict__ bsum, int* __restrict__ boff, int nB,
                      int* __restrict__ rowptr, int nN) {
    if (threadIdx.x == 0) {
        int run = 0;
        for (int i = 0; i < nB; ++i) { boff[i] = run; run += bsum[i]; }
        rowptr[nN] = run;
    }
}

__global__ void scanC(const int* __restrict__ degi, const int* __restrict__ boff,
                      int* __restrict__ rowptr, int* __restrict__ cursor, int nN) {
    __shared__ int s[256];
    int b = blockIdx.x, t = threadIdx.x;
    int base = b * 1024 + t * 4;
    int d[4]; int sum = 0;
#pragma unroll
    for (int k = 0; k < 4; ++k) { int i = base + k; d[k] = (i < nN) ? degi[i] : 0; sum += d[k]; }
    s[t] = sum; __syncthreads();
    for (int off = 1; off < 256; off <<= 1) {
        int u = (t >= off) ? s[t - off] : 0; __syncthreads();
        s[t] += u; __syncthreads();
    }
    int excl = s[t] - sum + boff[b];
#pragma unroll
    for (int k = 0; k < 4; ++k) {
        int i = base + k;
        if (i < nN) { rowptr[i] = excl; cursor[i] = excl; excl += d[k]; }
    }
}

__global__ void csr_fill(const int* __restrict__ src, const int* __restrict__ dst,
                         int* __restrict__ cursor, int* __restrict__ csr, int nE) {
    int e = blockIdx.x * blockDim.x + threadIdx.x;
    if (e < nE) {
        int pos = atomicAdd(&cursor[dst[e]], 1);
        csr[pos] = src[e];
    }
}

// ---------- g1 = (x @ W1) * dinv, stride 32 ----------
__global__ void gemm1_kernel(const float* __restrict__ x, const float* __restrict__ W1,
                             const float* __restrict__ dinv, float* __restrict__ G, int nN) {
    __shared__ float Ws[FEAT_IN * F1];
    for (int t = threadIdx.x; t < FEAT_IN * F1; t += blockDim.x) Ws[t] = W1[t];
    __syncthreads();
    int row = blockIdx.x * 8 + (threadIdx.x >> 5);
    if (row >= nN) return;
    int j = threadIdx.x & 31;
    const float* xr = x + (size_t)row * FEAT_IN;
    float acc = 0.f;
#pragma unroll 8
    for (int k = 0; k < FEAT_IN; ++k) acc = fmaf(xr[k], Ws[k * F1 + j], acc);
    G[(size_t)row * F1 + j] = acc * dinv[row];
}

// ---------- agg1: one node per wave, 8 edges x float4 in flight ----------
// x1 = relu(dinv*(self+sum) + b1); H = dinv*x1 (for layer 2); psum += x1
__global__ void agg1_kernel(const int* __restrict__ rowptr, const int* __restrict__ csr,
                            const float4* __restrict__ G4, const float* __restrict__ dinv,
                            const float* __restrict__ b1, const int* __restrict__ batch,
                            float4* __restrict__ H4, float* __restrict__ psum, int nN) {
    int node = blockIdx.x * 4 + (threadIdx.x >> 6);
    if (node >= nN) return;
    int lane = threadIdx.x & 63;
    int es = lane >> 3;        // edge sub-slot 0..7
    int comp = lane & 7;       // float4 component group: features comp*4..comp*4+3
    int beg = rowptr[node], end = rowptr[node + 1];
    float4 acc = make_float4(0.f, 0.f, 0.f, 0.f);
    for (int e = beg + es; e < end; e += 8) {
        int s = csr[e];
        float4 g = G4[(size_t)s * 8 + comp];
        acc.x += g.x; acc.y += g.y; acc.z += g.z; acc.w += g.w;
    }
#pragma unroll
    for (int m = 8; m < 64; m <<= 1) {
        acc.x += __shfl_xor(acc.x, m);
        acc.y += __shfl_xor(acc.y, m);
        acc.z += __shfl_xor(acc.z, m);
        acc.w += __shfl_xor(acc.w, m);
    }
    float4 self = G4[(size_t)node * 8 + comp];
    acc.x += self.x; acc.y += self.y; acc.z += self.z; acc.w += self.w;
    float dv = dinv[node];
    float4 b = ((const float4*)b1)[comp];
    float4 x1;
    x1.x = fmaxf(fmaf(dv, acc.x, b.x), 0.f);
    x1.y = fmaxf(fmaf(dv, acc.y, b.y), 0.f);
    x1.z = fmaxf(fmaf(dv, acc.z, b.z), 0.f);
    x1.w = fmaxf(fmaf(dv, acc.w, b.w), 0.f);
    if (es == 0) {
        H4[(size_t)node * 8 + comp] = make_float4(dv * x1.x, dv * x1.y, dv * x1.z, dv * x1.w);
        int bg = batch[node];
        float* ps = psum + (size_t)bg * FJ + comp * 4;
        atomicAdd(ps + 0, x1.x);
        atomicAdd(ps + 1, x1.y);
        atomicAdd(ps + 2, x1.z);
        atomicAdd(ps + 3, x1.w);
    }
}

// ---------- agg2: gather H (32-dim), then fused 32->64 GEMM + relu + pool ----------
__global__ void agg2_kernel(const int* __restrict__ rowptr, const int* __restrict__ csr,
                            const float4* __restrict__ H4, const float* __restrict__ dinv,
                            const float* __restrict__ W2, const float* __restrict__ b2,
                            const int* __restrict__ batch, float* __restrict__ psum, int nN) {
    __shared__ float W2s[F1 * F2];     // 8 KB
    __shared__ float aLds[4][F1];
    for (int t = threadIdx.x; t < F1 * F2; t += blockDim.x) W2s[t] = W2[t];
    int wv = threadIdx.x >> 6;
    int node = blockIdx.x * 4 + wv;
    int lane = threadIdx.x & 63;
    bool valid = node < nN;
    int es = lane >> 3, comp = lane & 7;
    float4 acc = make_float4(0.f, 0.f, 0.f, 0.f);
    if (valid) {
        int beg = rowptr[node], end = rowptr[node + 1];
        for (int e = beg + es; e < end; e += 8) {
            int s = csr[e];
            float4 g = H4[(size_t)s * 8 + comp];
            acc.x += g.x; acc.y += g.y; acc.z += g.z; acc.w += g.w;
        }
    }
#pragma unroll
    for (int m = 8; m < 64; m <<= 1) {
        acc.x += __shfl_xor(acc.x, m);
        acc.y += __shfl_xor(acc.y, m);
        acc.z += __shfl_xor(acc.z, m);
        acc.w += __shfl_xor(acc.w, m);
    }
    if (valid) {
        float4 self = H4[(size_t)node * 8 + comp];
        acc.x += self.x; acc.y += self.y; acc.z += self.z; acc.w += self.w;
        if (es == 0) ((float4*)aLds[wv])[comp] = acc;
    }
    __syncthreads();
    if (valid) {
        int j = lane;
        const float* a = aLds[wv];
        float dot = 0.f;
#pragma unroll
        for (int k = 0; k < F1; ++k) dot = fmaf(a[k], W2s[k * F2 + j], dot);
        float v = fmaf(dinv[node], dot, b2[j]);
        float x2 = fmaxf(v, 0.f);
        int bg = batch[node];
        atomicAdd(&psum[(size_t)bg * FJ + F1 + j], x2);
    }
}

__global__ void cnt_kernel(const int* __restrict__ batch, float* __restrict__ cnt, int nN) {
    int i = blockIdx.x * blockDim.x + threadIdx.x;
    if (i < nN) atomicAdd(&cnt[batch[i]], 1.0f);
}

// ---------- final MLP: one block (128 thr) per graph ----------
__global__ void mlp_kernel(const float* __restrict__ psum, const float* __restrict__ cnt,
                           const float* __restrict__ fW1, const float* __restrict__ fb1,
                           const float* __restrict__ fW2, const float* __restrict__ fb2,
                           float* __restrict__ out) {
    __shared__ float p[FJ];
    __shared__ float red[FH];
    int g = blockIdx.x, tid = threadIdx.x;
    float c = fmaxf(cnt[g], 1.0f);
    if (tid < FJ) p[tid] = psum[g * FJ + tid] / c;
    __syncthreads();
    float acc = fb1[tid];
    for (int k = 0; k < FJ; ++k) acc = fmaf(p[k], fW1[k * FH + tid], acc);
    float h = fmaxf(acc, 0.f);
    red[tid] = h * fW2[tid];
    __syncthreads();
    for (int s = FH / 2; s > 0; s >>= 1) {
        if (tid < s) red[tid] += red[tid + s];
        __syncthreads();
    }
    if (tid == 0) out[g] = red[0] + fb2[0];
}

extern "C" void kernel_launch(void* const* d_in, const int* in_sizes, int n_in,
                              void* d_out, int out_size, void* d_ws, size_t ws_size,
                              hipStream_t stream) {
    const float* x   = (const float*)d_in[0];
    const int*   ei  = (const int*)d_in[1];
    const int*   bat = (const int*)d_in[2];
    const float* W1  = (const float*)d_in[3];
    const float* b1  = (const float*)d_in[4];
    const float* W2  = (const float*)d_in[5];
    const float* b2  = (const float*)d_in[6];
    const float* fW1 = (const float*)d_in[7];
    const float* fb1 = (const float*)d_in[8];
    const float* fW2 = (const float*)d_in[9];
    const float* fb2 = (const float*)d_in[10];
    float* out = (float*)d_out;

    int nN = in_sizes[0] / FEAT_IN;
    int nE = in_sizes[1] / 2;
    int nG = out_size;
    const int* src = ei;
    const int* dst = ei + nE;

    int nB = (nN + 1023) / 1024;

    char* w = (char*)d_ws;
    int* degi    = (int*)w;            w += (size_t)nN * 4;
    int* rowptr  = (int*)w;            w += (size_t)(nN + 1) * 4;
    int* cursor  = (int*)w;            w += (size_t)nN * 4;
    int* bsum    = (int*)w;            w += (size_t)nB * 4;
    int* boff    = (int*)w;            w += (size_t)nB * 4;
    int* csr     = (int*)w;            w += (size_t)nE * 4;
    float* dinv  = (float*)w;          w += (size_t)nN * 4;
    float* G     = (float*)w;          w += (size_t)nN * F1 * 4;
    float* H     = (float*)w;          w += (size_t)nN * F1 * 4;
    float* psum  = (float*)w;          w += (size_t)nG * FJ * 4;
    float* cnt   = (float*)w;          w += (size_t)nG * 4;

    hipMemsetAsync(degi, 0, (size_t)nN * sizeof(int), stream);
    hipMemsetAsync(psum, 0, ((size_t)nG * FJ + nG) * sizeof(float), stream);

    // CSR build
    deg_count<<<(nE + 255) / 256, 256, 0, stream>>>(dst, degi, nE);
    dinv_kernel<<<(nN + 255) / 256, 256, 0, stream>>>(degi, dinv, nN);
    scanA<<<nB, 256, 0, stream>>>(degi, bsum, nN);
    scanB<<<1, 64, 0, stream>>>(bsum, boff, nB, rowptr, nN);
    scanC<<<nB, 256, 0, stream>>>(degi, boff, rowptr, cursor, nN);
    csr_fill<<<(nE + 255) / 256, 256, 0, stream>>>(src, dst, cursor, csr, nE);

    // layer 1: transform -> aggregate (+pool x1 fused)
    gemm1_kernel<<<(nN + 7) / 8, 256, 0, stream>>>(x, W1, dinv, G, nN);
    agg1_kernel<<<(nN + 3) / 4, 256, 0, stream>>>(rowptr, csr, (const float4*)G, dinv, b1, bat,
                                                  (float4*)H, psum, nN);
    // layer 2: aggregate (32-dim) -> transform (+pool x2 fused)
    agg2_kernel<<<(nN + 3) / 4, 256, 0, stream>>>(rowptr, csr, (const float4*)H, dinv, W2, b2,
                                                  bat, psum, nN);

    cnt_kernel<<<(nN + 255) / 256, 256, 0, stream>>>(bat, cnt, nN);
    mlp_kernel<<<nG, FH, 0, stream>>>(psum, cnt, fW1, fb1, fW2, fb2, out);
}